// Round 24
// baseline (88.904 us; speedup 1.0000x reference)
//
#include <hip/hip_runtime.h>
#include <math.h>

#define NB 32
#define CIN 32
#define DIM 32
#define KK 5
#define VALID 17
#define CVOL (VALID*VALID*VALID)   // 4913
#define PW 1024                    // plane words (32*32), linear
#define PLN 9                      // planes for a d-triple: ids 6p-2 .. 6p+6
#define SLABF (PLN*PW + 4)         // +4: wq7 vb over-read at last row of last plane

// ws layout (floats): [0,4000) w_eff ; [4000] B ; [4096, ...) C partials [nsplit][32][4913]

__global__ __launch_bounds__(256) void prep_kernel(const float* __restrict__ weight,
                                                   const float* __restrict__ bias,
                                                   float* __restrict__ ws) {
    int idx = blockIdx.x * 256 + threadIdx.x;
    if (idx < 4000) {
        float s = 0.f;
        #pragma unroll 8
        for (int co = 0; co < 64; ++co) s += weight[co * 4000 + idx];
        ws[idx] = s;
    }
    if (idx == 0) {
        float b = 0.f;
        for (int i = 0; i < 64; ++i) b += bias[i];
        ws[4000] = b;
    }
}

__device__ __forceinline__ void gload_lds16(const float* g, float* l) {
    __builtin_amdgcn_global_load_lds((const __attribute__((address_space(1))) void*)g,
                                     (__attribute__((address_space(3))) void*)l,
                                     16, 0, 0);
}

// Block = (split s, n, d-TRIPLE p), 384 threads = 6 waves (r22 geometry — best measured).
// wv = tid>>6: dq = wv>>1 in {0,1,2} (d = 3p+dq), hb = wv&1. lane: hg = lane>>3, wq = lane&7.
// Wave hb=0: h = hg (0..7) + [hg7: h=16 tail, kh 0,1]. Wave hb=1: h = 8+hg.
// r24: vb read from LDS again (r12 pattern) instead of DPP+cndmask — at 24 waves/CU the
// VALU is ~60% busy (r23 back-solve) while the LDS pipe is ~25%; moving 6 VALU ops/tap to
// 1 conflict-free ds_read rebalances. wq7's vb FMAs exec-masked (its true taps are zero-pad).
// NOTE: no min-waves launch-bound arg (r10: forced VGPR squeeze = spill, 6x; r23: VGPR=32, +25%).
__global__ __launch_bounds__(384) void conv_kernel(const float* __restrict__ x,
                                                   const float* __restrict__ weff,
                                                   float* __restrict__ C,
                                                   int cpS) {
    __shared__ __align__(16) float slab[SLABF];
    const int b = blockIdx.x;
    const int s = b / (NB * 6);
    const int rem = b - s * (NB * 6);
    const int n = rem / 6;
    const int p = rem - n * 6;
    const int tid = threadIdx.x;
    const int wv = tid >> 6;
    const int dq = wv >> 1;
    const int hb = wv & 1;
    const int lane = tid & 63;
    const int hg = lane >> 3;
    const int wq = lane & 7;
    const int d = 3 * p + dq;
    const bool dok = (d < VALID);
    const int h = hb ? (8 + hg) : hg;
    const bool tall = (hb == 0) && (hg == 7);   // even waves' hg7 also do h=16
    const bool w7ok = (wq < 7);
    const bool w0t  = (wq == 0);

    // zero slab once: OOB planes (never staged) must read as 0
    for (int t = tid; t < SLABF / 4; t += 384) ((float4*)slab)[t] = make_float4(0.f, 0.f, 0.f, 0.f);
    __syncthreads();

    const int id0 = 6 * p - 2;
    const int cin0 = s * cpS;

    float acc0 = 0.f, acc1 = 0.f, aw0 = 0.f;
    float accT0 = 0.f, accT1 = 0.f, awT = 0.f;

    for (int ci = 0; ci < cpS; ++ci) {
        // stage: 36 slots (9 planes x 4 x 1KB); wave wv issues slots [6wv, 6wv+6)
        const float* xc = x + ((size_t)n * CIN + (cin0 + ci)) * (DIM * DIM * DIM);
        #pragma unroll
        for (int st = 0; st < 6; ++st) {
            int slot = wv * 6 + st;           // wave-uniform
            int pi = slot >> 2, c = slot & 3;
            int id = id0 + pi;
            if (id >= 0 && id < DIM) {        // wave-uniform guard
                gload_lds16(xc + (size_t)id * PW + c * 256 + lane * 4,
                            slab + pi * PW + c * 256);
            }
        }
        __syncthreads();   // staged data visible

        const float* wb = weff + (cin0 + ci) * 125;
        #pragma unroll
        for (int kd = 0; kd < KK; ++kd) {
            const float* plane = slab + (2 * dq + kd) * PW;
            #pragma unroll
            for (int kh = 0; kh < KK; ++kh) {
                const int ih = 2 * h - 2 + kh;
                if ((unsigned)ih < 32u) {      // hg-uniform predicate
                    const float* rp = plane + ih * 32 + 4 * wq;
                    const float4 va = *(const float4*)rp;
                    const float4 vb = *(const float4*)(rp + 4);  // wq7: garbage, masked below
                    const float w0 = wb[kd * 25 + kh * 5 + 0];
                    const float w1 = wb[kd * 25 + kh * 5 + 1];
                    const float w2 = wb[kd * 25 + kh * 5 + 2];
                    const float w3 = wb[kd * 25 + kh * 5 + 3];
                    const float w4 = wb[kd * 25 + kh * 5 + 4];
                    acc0 = fmaf(w0, va.x, acc0);
                    acc1 = fmaf(w0, va.z, acc1);
                    acc0 = fmaf(w1, va.y, acc0);
                    acc1 = fmaf(w1, va.w, acc1);
                    acc0 = fmaf(w2, va.z, acc0);
                    acc0 = fmaf(w3, va.w, acc0);
                    if (w7ok) {   // wq7's vb taps are true zero-pad (iw>=32): skip
                        acc0 = fmaf(w4, vb.x, acc0);
                        acc1 = fmaf(w2, vb.x, acc1);
                        acc1 = fmaf(w3, vb.y, acc1);
                        acc1 = fmaf(w4, vb.z, acc1);
                    }
                    aw0  = fmaf(w2, va.x, aw0);
                    aw0  = fmaf(w3, va.y, aw0);
                    aw0  = fmaf(w4, va.z, aw0);
                }
            }
            if (tall) {   // h=16: ih = 30+kh valid only for kh 0,1 (group-uniform predicate)
                #pragma unroll
                for (int kh = 0; kh < 2; ++kh) {
                    const float* rp = plane + (30 + kh) * 32 + 4 * wq;
                    const float4 va = *(const float4*)rp;
                    const float4 vb = *(const float4*)(rp + 4);
                    const float w0 = wb[kd * 25 + kh * 5 + 0];
                    const float w1 = wb[kd * 25 + kh * 5 + 1];
                    const float w2 = wb[kd * 25 + kh * 5 + 2];
                    const float w3 = wb[kd * 25 + kh * 5 + 3];
                    const float w4 = wb[kd * 25 + kh * 5 + 4];
                    accT0 = fmaf(w0, va.x, accT0);
                    accT1 = fmaf(w0, va.z, accT1);
                    accT0 = fmaf(w1, va.y, accT0);
                    accT1 = fmaf(w1, va.w, accT1);
                    accT0 = fmaf(w2, va.z, accT0);
                    accT0 = fmaf(w3, va.w, accT0);
                    if (w7ok) {
                        accT0 = fmaf(w4, vb.x, accT0);
                        accT1 = fmaf(w2, vb.x, accT1);
                        accT1 = fmaf(w3, vb.y, accT1);
                        accT1 = fmaf(w4, vb.z, accT1);
                    }
                    awT   = fmaf(w2, va.x, awT);
                    awT   = fmaf(w3, va.y, awT);
                    awT   = fmaf(w4, va.z, awT);
                }
            }
        }
        __syncthreads();   // WAR: next stage overwrites slab
    }

    if (dok) {
        float* Cn = C + ((size_t)s * NB + n) * CVOL + (size_t)d * (VALID * VALID);
        Cn[h * VALID + 2 * wq + 1] = acc0;
        Cn[h * VALID + 2 * wq + 2] = acc1;
        if (w0t) Cn[h * VALID] = aw0;
        if (tall) {
            Cn[16 * VALID + 2 * wq + 1] = accT0;
            Cn[16 * VALID + 2 * wq + 2] = accT1;
            if (w0t) Cn[16 * VALID] = awT;
        }
    }
}

// Blocks 0..863: one wave per active cell (n, i<3, j<3, k<3); lane = p1-subcell;
// fused nsplit reduction; butterfly sum. Blocks 864..988: constant fill.
__global__ __launch_bounds__(64) void pool_kernel(const float* __restrict__ C,
                                                  const float* __restrict__ wsB,
                                                  float* __restrict__ out,
                                                  int nsplit) {
    const int b = blockIdx.x;
    const int l = threadIdx.x;
    const float B = wsB[0];

    if (b < 864) {
        const int n = b / 27;
        const int cell = b - n * 27;
        const int ci = cell / 9, cj = (cell / 3) % 3, ck = cell % 3;
        float v = 0.f;
        if (l < 27) {
            const int da = l / 9, db = (l / 3) % 3, dc = l % 3;
            const int pz = 3 * ci + da, py = 3 * cj + db, px = 3 * ck + dc;
            const float* Cn = C + (size_t)n * CVOL;
            float m = -INFINITY;
            #pragma unroll
            for (int dz = 0; dz < 2; ++dz)
            #pragma unroll
            for (int dy = 0; dy < 2; ++dy)
            #pragma unroll
            for (int dx = 0; dx < 2; ++dx) {
                int z = 2 * pz + dz, y = 2 * py + dy, xx = 2 * px + dx;
                float t;
                if (z < VALID && y < VALID && xx < VALID) {
                    size_t off = ((size_t)z * VALID + y) * VALID + xx;
                    float sum = 0.f;
                    for (int ss = 0; ss < nsplit; ++ss)
                        sum += Cn[(size_t)ss * NB * CVOL + off];
                    t = sum + B;
                } else {
                    t = B;
                }
                m = fmaxf(m, t);
            }
            v = m;
        }
        #pragma unroll
        for (int off = 32; off > 0; off >>= 1) v += __shfl_xor(v, off, 64);
        if (l == 0) out[n * 1000 + ci * 100 + cj * 10 + ck] = v;
    } else {
        const int fb = b - 864;           // 0..124
        #pragma unroll
        for (int t = 0; t < 4; ++t) {
            int idx = fb * 256 + 64 * t + l;
            if (idx < 32000) {
                int r = idx % 1000;
                int i = r / 100, j = (r / 10) % 10, k = r % 10;
                if (i >= 3 || j >= 3 || k >= 3) out[idx] = 27.f * B;
            }
        }
    }
}

extern "C" void kernel_launch(void* const* d_in, const int* in_sizes, int n_in,
                              void* d_out, int out_size, void* d_ws, size_t ws_size,
                              hipStream_t stream) {
    const float* x      = (const float*)d_in[0];
    const float* weight = (const float*)d_in[1];
    const float* bias   = (const float*)d_in[2];
    float* out = (float*)d_out;
    float* ws  = (float*)d_ws;
    float* weff = ws;
    float* wsB  = ws + 4000;
    float* C    = ws + 4096;

    // nsplit=4: cpS=8 amortizes prologue; 768 blocks fully co-resident (4/CU x 256).
    int nsplit = 1;
    if      (ws_size >= (size_t)(4096 + 4 * NB * CVOL) * 4) nsplit = 4;
    else if (ws_size >= (size_t)(4096 + 2 * NB * CVOL) * 4) nsplit = 2;
    int cpS = CIN / nsplit;

    prep_kernel<<<dim3(16), dim3(256), 0, stream>>>(weight, bias, ws);
    conv_kernel<<<dim3(nsplit * NB * 6), dim3(384), 0, stream>>>(x, weff, C, cpS);
    pool_kernel<<<dim3(989), dim3(64), 0, stream>>>(C, wsB, out, nsplit);
}

// Round 25
// 73.929 us; speedup vs baseline: 1.2026x; 1.2026x over previous
//
#include <hip/hip_runtime.h>
#include <math.h>

#define NB 32
#define CIN 32
#define DIM 32
#define KK 5
#define VALID 17
#define CVOL (VALID*VALID*VALID)   // 4913
#define PW 1024                    // plane words (32*32), linear
#define PLN 9                      // planes for a d-triple: ids 6p-2 .. 6p+6
#define SLABF (PLN*PW + 4)         // 36880 B -> 4 blocks/CU (384 thr = 24 waves/CU)

// ws layout (floats): [0,4000) w_eff ; [4000] B ; [4096, ...) C partials [nsplit][32][4913]

__global__ __launch_bounds__(256) void prep_kernel(const float* __restrict__ weight,
                                                   const float* __restrict__ bias,
                                                   float* __restrict__ ws) {
    int idx = blockIdx.x * 256 + threadIdx.x;
    if (idx < 4000) {
        float s = 0.f;
        #pragma unroll 8
        for (int co = 0; co < 64; ++co) s += weight[co * 4000 + idx];
        ws[idx] = s;
    }
    if (idx == 0) {
        float b = 0.f;
        for (int i = 0; i < 64; ++i) b += bias[i];
        ws[4000] = b;
    }
}

__device__ __forceinline__ void gload_lds16(const float* g, float* l) {
    __builtin_amdgcn_global_load_lds((const __attribute__((address_space(1))) void*)g,
                                     (__attribute__((address_space(3))) void*)l,
                                     16, 0, 0);
}

// shfl_down-by-1 (lane i <- i+1) via row_shl:1 — verified r16 (absmax 0).
// MUST be unconditional-in-straight-line (r17 convergence bug: ternary-wrapped DPP
// exec-masked the source lane -> lane 6 lost taps).
__device__ __forceinline__ float dpp_shl1(float v) {
    return __int_as_float(__builtin_amdgcn_update_dpp(0, __float_as_int(v),
                                                      0x101 /*row_shl:1*/, 0xF, 0xF, true));
}

// Block = (split s, n, d-TRIPLE p), 384 threads = 6 waves. [r22 — best measured: 74.0 us]
// wv = tid>>6: dq = wv>>1 in {0,1,2} (d = 3p+dq), hb = wv&1. lane: hg = lane>>3, wq = lane&7.
// Wave hb=0: h = hg (0..7) + [hg7: h=16 tail, kh 0,1]. Wave hb=1: h = 8+hg.
// Slab: 9 linear planes, pi = id-(6p-2); kd plane of d: pi = 2dq+kd.
// vb via DPP (r24 showed LDS-vb regresses: conflicts 4x, VGPR 40, +9us). d-quint (r23)
// regresses via VGPR=32 squeeze. nsplit=4, 768 blocks fully co-resident (4/CU x 256).
// NOTE: no min-waves launch-bound arg (r10 spill 6x; r23 VGPR squeeze +25%).
__global__ __launch_bounds__(384) void conv_kernel(const float* __restrict__ x,
                                                   const float* __restrict__ weff,
                                                   float* __restrict__ C,
                                                   int cpS) {
    __shared__ __align__(16) float slab[SLABF];
    const int b = blockIdx.x;
    const int s = b / (NB * 6);
    const int rem = b - s * (NB * 6);
    const int n = rem / 6;
    const int p = rem - n * 6;
    const int tid = threadIdx.x;
    const int wv = tid >> 6;
    const int dq = wv >> 1;
    const int hb = wv & 1;
    const int lane = tid & 63;
    const int hg = lane >> 3;
    const int wq = lane & 7;
    const int d = 3 * p + dq;
    const bool dok = (d < VALID);
    const int h = hb ? (8 + hg) : hg;
    const bool tall = (hb == 0) && (hg == 7);   // even waves' hg7 also do h=16
    const bool w7ok = (wq < 7);
    const bool w0t  = (wq == 0);

    // zero slab once: OOB planes (never staged) must read as 0
    for (int t = tid; t < SLABF / 4; t += 384) ((float4*)slab)[t] = make_float4(0.f, 0.f, 0.f, 0.f);
    __syncthreads();

    const int id0 = 6 * p - 2;
    const int cin0 = s * cpS;

    float acc0 = 0.f, acc1 = 0.f, aw0 = 0.f;
    float accT0 = 0.f, accT1 = 0.f, awT = 0.f;

    for (int ci = 0; ci < cpS; ++ci) {
        // stage: 36 slots (9 planes x 4 x 1KB); wave wv issues slots [6wv, 6wv+6)
        const float* xc = x + ((size_t)n * CIN + (cin0 + ci)) * (DIM * DIM * DIM);
        #pragma unroll
        for (int st = 0; st < 6; ++st) {
            int slot = wv * 6 + st;           // wave-uniform
            int pi = slot >> 2, c = slot & 3;
            int id = id0 + pi;
            if (id >= 0 && id < DIM) {        // wave-uniform guard
                gload_lds16(xc + (size_t)id * PW + c * 256 + lane * 4,
                            slab + pi * PW + c * 256);
            }
        }
        __syncthreads();   // staged data visible

        const float* wb = weff + (cin0 + ci) * 125;
        #pragma unroll
        for (int kd = 0; kd < KK; ++kd) {
            const float* plane = slab + (2 * dq + kd) * PW;
            #pragma unroll
            for (int kh = 0; kh < KK; ++kh) {
                const int ih = 2 * h - 2 + kh;
                if ((unsigned)ih < 32u) {      // hg-uniform predicate
                    const float4 va = *(const float4*)(plane + ih * 32 + 4 * wq);
                    const float t0 = dpp_shl1(va.x);
                    const float t1 = dpp_shl1(va.y);
                    const float t2 = dpp_shl1(va.z);
                    const float vb0 = w7ok ? t0 : 0.f;
                    const float vb1 = w7ok ? t1 : 0.f;
                    const float vb2 = w7ok ? t2 : 0.f;
                    const float w0 = wb[kd * 25 + kh * 5 + 0];
                    const float w1 = wb[kd * 25 + kh * 5 + 1];
                    const float w2 = wb[kd * 25 + kh * 5 + 2];
                    const float w3 = wb[kd * 25 + kh * 5 + 3];
                    const float w4 = wb[kd * 25 + kh * 5 + 4];
                    acc0 = fmaf(w0, va.x, acc0);
                    acc1 = fmaf(w0, va.z, acc1);
                    acc0 = fmaf(w1, va.y, acc0);
                    acc1 = fmaf(w1, va.w, acc1);
                    acc0 = fmaf(w2, va.z, acc0);
                    acc1 = fmaf(w2, vb0, acc1);
                    acc0 = fmaf(w3, va.w, acc0);
                    acc1 = fmaf(w3, vb1, acc1);
                    acc0 = fmaf(w4, vb0, acc0);
                    acc1 = fmaf(w4, vb2, acc1);
                    aw0  = fmaf(w2, va.x, aw0);
                    aw0  = fmaf(w3, va.y, aw0);
                    aw0  = fmaf(w4, va.z, aw0);
                }
            }
            if (tall) {   // h=16: ih = 30+kh valid only for kh 0,1 (group-uniform predicate)
                #pragma unroll
                for (int kh = 0; kh < 2; ++kh) {
                    const float4 va = *(const float4*)(plane + (30 + kh) * 32 + 4 * wq);
                    const float t0 = dpp_shl1(va.x);
                    const float t1 = dpp_shl1(va.y);
                    const float t2 = dpp_shl1(va.z);
                    const float vb0 = w7ok ? t0 : 0.f;
                    const float vb1 = w7ok ? t1 : 0.f;
                    const float vb2 = w7ok ? t2 : 0.f;
                    const float w0 = wb[kd * 25 + kh * 5 + 0];
                    const float w1 = wb[kd * 25 + kh * 5 + 1];
                    const float w2 = wb[kd * 25 + kh * 5 + 2];
                    const float w3 = wb[kd * 25 + kh * 5 + 3];
                    const float w4 = wb[kd * 25 + kh * 5 + 4];
                    accT0 = fmaf(w0, va.x, accT0);
                    accT1 = fmaf(w0, va.z, accT1);
                    accT0 = fmaf(w1, va.y, accT0);
                    accT1 = fmaf(w1, va.w, accT1);
                    accT0 = fmaf(w2, va.z, accT0);
                    accT1 = fmaf(w2, vb0, accT1);
                    accT0 = fmaf(w3, va.w, accT0);
                    accT1 = fmaf(w3, vb1, accT1);
                    accT0 = fmaf(w4, vb0, accT0);
                    accT1 = fmaf(w4, vb2, accT1);
                    awT   = fmaf(w2, va.x, awT);
                    awT   = fmaf(w3, va.y, awT);
                    awT   = fmaf(w4, va.z, awT);
                }
            }
        }
        __syncthreads();   // WAR: next stage overwrites slab
    }

    if (dok) {
        float* Cn = C + ((size_t)s * NB + n) * CVOL + (size_t)d * (VALID * VALID);
        Cn[h * VALID + 2 * wq + 1] = acc0;
        Cn[h * VALID + 2 * wq + 2] = acc1;
        if (w0t) Cn[h * VALID] = aw0;
        if (tall) {
            Cn[16 * VALID + 2 * wq + 1] = accT0;
            Cn[16 * VALID + 2 * wq + 2] = accT1;
            if (w0t) Cn[16 * VALID] = awT;
        }
    }
}

// Blocks 0..863: one wave per active cell (n, i<3, j<3, k<3); lane = p1-subcell;
// fused nsplit reduction; butterfly sum. Blocks 864..988: constant fill.
__global__ __launch_bounds__(64) void pool_kernel(const float* __restrict__ C,
                                                  const float* __restrict__ wsB,
                                                  float* __restrict__ out,
                                                  int nsplit) {
    const int b = blockIdx.x;
    const int l = threadIdx.x;
    const float B = wsB[0];

    if (b < 864) {
        const int n = b / 27;
        const int cell = b - n * 27;
        const int ci = cell / 9, cj = (cell / 3) % 3, ck = cell % 3;
        float v = 0.f;
        if (l < 27) {
            const int da = l / 9, db = (l / 3) % 3, dc = l % 3;
            const int pz = 3 * ci + da, py = 3 * cj + db, px = 3 * ck + dc;
            const float* Cn = C + (size_t)n * CVOL;
            float m = -INFINITY;
            #pragma unroll
            for (int dz = 0; dz < 2; ++dz)
            #pragma unroll
            for (int dy = 0; dy < 2; ++dy)
            #pragma unroll
            for (int dx = 0; dx < 2; ++dx) {
                int z = 2 * pz + dz, y = 2 * py + dy, xx = 2 * px + dx;
                float t;
                if (z < VALID && y < VALID && xx < VALID) {
                    size_t off = ((size_t)z * VALID + y) * VALID + xx;
                    float sum = 0.f;
                    for (int ss = 0; ss < nsplit; ++ss)
                        sum += Cn[(size_t)ss * NB * CVOL + off];
                    t = sum + B;
                } else {
                    t = B;
                }
                m = fmaxf(m, t);
            }
            v = m;
        }
        #pragma unroll
        for (int off = 32; off > 0; off >>= 1) v += __shfl_xor(v, off, 64);
        if (l == 0) out[n * 1000 + ci * 100 + cj * 10 + ck] = v;
    } else {
        const int fb = b - 864;           // 0..124
        #pragma unroll
        for (int t = 0; t < 4; ++t) {
            int idx = fb * 256 + 64 * t + l;
            if (idx < 32000) {
                int r = idx % 1000;
                int i = r / 100, j = (r / 10) % 10, k = r % 10;
                if (i >= 3 || j >= 3 || k >= 3) out[idx] = 27.f * B;
            }
        }
    }
}

extern "C" void kernel_launch(void* const* d_in, const int* in_sizes, int n_in,
                              void* d_out, int out_size, void* d_ws, size_t ws_size,
                              hipStream_t stream) {
    const float* x      = (const float*)d_in[0];
    const float* weight = (const float*)d_in[1];
    const float* bias   = (const float*)d_in[2];
    float* out = (float*)d_out;
    float* ws  = (float*)d_ws;
    float* weff = ws;
    float* wsB  = ws + 4000;
    float* C    = ws + 4096;

    // nsplit=4: cpS=8 amortizes prologue; 768 blocks fully co-resident (4/CU x 256).
    int nsplit = 1;
    if      (ws_size >= (size_t)(4096 + 4 * NB * CVOL) * 4) nsplit = 4;
    else if (ws_size >= (size_t)(4096 + 2 * NB * CVOL) * 4) nsplit = 2;
    int cpS = CIN / nsplit;

    prep_kernel<<<dim3(16), dim3(256), 0, stream>>>(weight, bias, ws);
    conv_kernel<<<dim3(nsplit * NB * 6), dim3(384), 0, stream>>>(x, weff, C, cpS);
    pool_kernel<<<dim3(989), dim3(64), 0, stream>>>(C, wsB, out, nsplit);
}